// Round 2
// baseline (534.915 us; speedup 1.0000x reference)
//
#include <hip/hip_runtime.h>

namespace {
constexpr int CH = 6;
constexpr int H  = 1024;
constexpr int W  = 1024;
constexpr int ROWS = 4;                           // output rows per thread
constexpr float P_BURN  = 0.58f;
constexpr float W_WIND  = 0.045f;
constexpr float W_SLOPE = 0.078f;
constexpr float C45     = 0.70710678118654752f;   // sqrt(2)/2
constexpr float DEG2RAD = 0.017453292519943295f;  // pi/180

struct Row6 { float v[6]; };

// Load elements [j0-1 .. j0+4] of one row; zero outside the image.
// Halo elements come from neighbor lanes via shuffle (lanes are x-consecutive
// within a wave); only lanes 0/63 fall back to a scalar edge load.
// `row` is wave-uniform, so the early-out branch is non-divergent.
__device__ __forceinline__ Row6 load_row(const float* __restrict__ plane,
                                         int row, int j0, int lane) {
    Row6 r;
    if ((unsigned)row >= (unsigned)H) {
#pragma unroll
        for (int t = 0; t < 6; ++t) r.v[t] = 0.f;
        return r;
    }
    const float* p = plane + (size_t)row * W;
    const float4 m = *reinterpret_cast<const float4*>(p + j0);   // 16B aligned
    float left  = __shfl_up(m.w, 1);
    float right = __shfl_down(m.x, 1);
    if (lane == 0)  left  = (j0 > 0)     ? p[j0 - 1] : 0.f;
    if (lane == 63) right = (j0 + 4 < W) ? p[j0 + 4] : 0.f;
    r.v[0] = left; r.v[1] = m.x; r.v[2] = m.y; r.v[3] = m.z; r.v[4] = m.w;
    r.v[5] = right;
    return r;
}
}  // namespace

__global__ __launch_bounds__(256)
void fire_step(const float* __restrict__ x, float* __restrict__ out, int B) {
    const int W4 = W / 4;
    const int lane = threadIdx.x & 63;
    const int gid  = blockIdx.x * 256 + threadIdx.x;
    const int j0   = (gid % W4) * 4;
    const int rest = gid / W4;
    const int i0   = (rest % (H / ROWS)) * ROWS;
    const int b    = rest / (H / ROWS);
    if (b >= B) return;

    const size_t plane = (size_t)H * W;
    const float* base_b = x + (size_t)b * CH * plane;
    const float* elev  = base_b + 0 * plane;
    const float* wsp   = base_b + 1 * plane;
    const float* wdp   = base_b + 2 * plane;
    const float* hump  = base_b + 3 * plane;
    const float* ndvip = base_b + 4 * plane;
    const float* fsp   = base_b + 5 * plane;
    float* outp = out + (size_t)b * plane;

    // Rolling window of 3 rows for elev and fire.
    Row6 em = load_row(elev, i0 - 1, j0, lane);
    Row6 ec = load_row(elev, i0,     j0, lane);
    Row6 fm = load_row(fsp,  i0 - 1, j0, lane);
    Row6 fc = load_row(fsp,  i0,     j0, lane);

#pragma unroll
    for (int r = 0; r < ROWS; ++r) {
        const int i = i0 + r;
        const Row6 ep = load_row(elev, i + 1, j0, lane);
        const Row6 fq = load_row(fsp,  i + 1, j0, lane);

        const size_t roff = (size_t)i * W + j0;
        const float4 ws4 = *reinterpret_cast<const float4*>(wsp   + roff);
        const float4 wd4 = *reinterpret_cast<const float4*>(wdp   + roff);
        const float4 hu4 = *reinterpret_cast<const float4*>(hump  + roff);
        const float4 nd4 = *reinterpret_cast<const float4*>(ndvip + roff);
        const float* wsa = reinterpret_cast<const float*>(&ws4);
        const float* wda = reinterpret_cast<const float*>(&wd4);
        const float* hua = reinterpret_cast<const float*>(&hu4);
        const float* nda = reinterpret_cast<const float*>(&nd4);

        float o[4];
#pragma unroll
        for (int k = 0; k < 4; ++k) {
            // Sobel/8 with zero padding
            const float dx = ((em.v[k+2] - em.v[k]) + 2.f * (ec.v[k+2] - ec.v[k]) +
                              (ep.v[k+2] - ep.v[k])) * 0.125f;
            const float dy = ((ep.v[k]   - em.v[k]) + 2.f * (ep.v[k+1] - em.v[k+1]) +
                              (ep.v[k+2] - em.v[k+2])) * 0.125f;
            const float g = sqrtf(dx * dx + dy * dy + 1e-8f);
            // tan(atan(g)) == g  ->  slope_effect = 1 + W_SLOPE*g
            const float slope_eff = 1.f + W_SLOPE * g;
            const float moist = fminf(fmaxf(1.f - 400.f * hua[k], 0.3f), 1.f);
            const float veg   = 0.5f + 0.5f * fminf(fmaxf(nda[k], 0.f), 1.f);
            const float basep = P_BURN * slope_eff * moist * veg;

            // wind_math = mod(270-wd,360) deg; sin/cos are periodic -> drop mod.
            const float wrad = (270.f - wda[k]) * DEG2RAD;
            float sw, cw;
            __sincosf(wrad, &sw, &cw);

            // max over burning neighbors of cos(d_angle - wind_math)
            float best = -2.f;
            if (fm.v[k+1] > 0.5f) best = fmaxf(best,  sw);              //  90
            if (fm.v[k+2] > 0.5f) best = fmaxf(best,  C45 * (cw + sw)); //  45
            if (fc.v[k+2] > 0.5f) best = fmaxf(best,  cw);              //   0
            if (fq.v[k+2] > 0.5f) best = fmaxf(best,  C45 * (cw - sw)); // 315
            if (fq.v[k+1] > 0.5f) best = fmaxf(best, -sw);              // 270
            if (fq.v[k]   > 0.5f) best = fmaxf(best, -C45 * (cw + sw)); // 225
            if (fc.v[k]   > 0.5f) best = fmaxf(best, -cw);              // 180
            if (fm.v[k]   > 0.5f) best = fmaxf(best,  C45 * (sw - cw)); // 135

            float prob = 0.f;
            if (best > -1.5f) {  // at least one burning neighbor
                const float wf = 1.f + W_WIND * best * wsa[k];
                prob = fminf(fmaxf(basep * wf, 0.f), 1.f);
            }
            const float fsc = fc.v[k + 1];
            o[k] = fmaxf(fsc, (fsc < 0.5f) ? prob : 0.f);
        }

        float4 ov;
        ov.x = o[0]; ov.y = o[1]; ov.z = o[2]; ov.w = o[3];
        *reinterpret_cast<float4*>(outp + roff) = ov;

        // rotate the rolling window
        em = ec; ec = ep; fm = fc; fc = fq;
    }
}

extern "C" void kernel_launch(void* const* d_in, const int* in_sizes, int n_in,
                              void* d_out, int out_size, void* d_ws, size_t ws_size,
                              hipStream_t stream) {
    const float* x = (const float*)d_in[0];
    float* out = (float*)d_out;
    const int B = in_sizes[0] / (CH * H * W);          // 16
    const int total_threads = B * (H / ROWS) * (W / 4);
    const int blocks = (total_threads + 255) / 256;
    fire_step<<<blocks, 256, 0, stream>>>(x, out, B);
}